// Round 11
// baseline (398.550 us; speedup 1.0000x reference)
//
#include <hip/hip_runtime.h>

#define T 1024
#define BATCH 512
#define EMB 64
#define HID 64
#define NGATE 256
#define VOCABP1 50001

typedef unsigned int uint32;
typedef unsigned short u16;
typedef __attribute__((ext_vector_type(8))) short short8;   // 8 bf16 = 4 VGPRs
typedef __attribute__((ext_vector_type(4))) float f32x4;    // MFMA C/D
typedef __attribute__((ext_vector_type(4))) float float4v;
typedef __attribute__((ext_vector_type(4))) int int4v;

#define L2E 1.44269504088896340736f

__device__ __forceinline__ float rcpf(float x) { return __builtin_amdgcn_rcpf(x); }
__device__ __forceinline__ float exp2as(float x) {   // raw v_exp_f32 (= 2^x)
    float r;
    asm("v_exp_f32 %0, %1" : "=v"(r) : "v"(x));
    return r;
}
// gate activations on PRE-SCALED z (weights folded with -log2e / 2log2e):
__device__ __forceinline__ float sigm_pre(float z)  { return rcpf(1.0f + exp2as(z)); }
__device__ __forceinline__ float tanh_pre(float z)  { return fmaf(-2.0f, rcpf(exp2as(z) + 1.0f), 1.0f); }
__device__ __forceinline__ float tanh_c(float c)    { return tanh_pre(c * (2.0f * L2E)); }

__device__ __forceinline__ u16 f2bf(float x) {        // RNE f32->bf16
    uint32 u = __float_as_uint(x);
    u += 0x7fffu + ((u >> 16) & 1u);
    return (u16)(u >> 16);
}
__device__ __forceinline__ float bf2f(u16 h) { return __uint_as_float(((uint32)h) << 16); }

// LDS-only barrier: drains lgkmcnt but leaves global loads in flight.
#define BARRIER_LDS() asm volatile("s_waitcnt lgkmcnt(0)\n\ts_barrier" ::: "memory")

// ---------------------------------------------------------------------------
// Fused prep: ONE dispatch covering
//   blocks [0,2048):    xstream  — A-fragment emb stream, f32->bf16
//   blocks [2048,2176): maskprep — mask bit-words
//   blocks [2176,2192): bfrag    — B fragments, 16-way parallel
//   block  2192:        zero the 128 mlp pair-handshake flags
// NOTE (r9 lesson): the xstream precompute is load-bearing — its 2048-block
// dispatch has the TLP to absorb the random emb gather; inlining the gather
// into the 1-wave/SIMD lstm loop regressed 290->427 us (FETCH 50->82 MB).
// ---------------------------------------------------------------------------
__global__ void prep_kernel(const int* __restrict__ x, const float* __restrict__ emb,
                            const float* __restrict__ Uf, const float* __restrict__ Ub,
                            const float* __restrict__ Wf, const float* __restrict__ Wb,
                            u16* __restrict__ xstream, uint32* __restrict__ mbits,
                            u16* __restrict__ bfrag, uint32* __restrict__ flags)
{
    const int bid = blockIdx.x;
    const int tid = threadIdx.x;

    if (bid < 2048) {
        // ---- xstream ----
        const int gb    = bid >> 6;
        const int stile = bid & 63;
        const int lane  = tid & 63;
        const int half  = tid >> 6;
        const int ks    = half & 1;
        const int sp    = half >> 1;
        const int m     = lane & 15;
        const int qj    = (lane >> 4) * 8;
        // 8 consecutive tokens as 2 x int4 (base 32B-aligned)
        const int4v* xp = (const int4v*)(x + (gb * 16 + m) * T + stile * 16 + sp * 8);
        const int4v t0 = xp[0];
        const int4v t1 = xp[1];
#pragma unroll
        for (int i = 0; i < 8; ++i) {
            const int s   = stile * 16 + sp * 8 + i;
            const int tok = (i < 4) ? t0[i & 3] : t1[i & 3];
            const float* er = emb + (size_t)tok * EMB + ks * 32 + qj;
            const float4v a = *(const float4v*)er;
            const float4v b = *(const float4v*)(er + 4);
            short8 v;
            v[0] = (short)f2bf(a[0]); v[1] = (short)f2bf(a[1]);
            v[2] = (short)f2bf(a[2]); v[3] = (short)f2bf(a[3]);
            v[4] = (short)f2bf(b[0]); v[5] = (short)f2bf(b[1]);
            v[6] = (short)f2bf(b[2]); v[7] = (short)f2bf(b[3]);
            *(short8*)(xstream + ((size_t)(gb * 1024 + s) * 128 + ks * 64 + lane) * 8) = v;
        }
    } else if (bid < 2048 + 128) {
        // ---- maskprep ----
        const int idx  = (bid - 2048) * 256 + tid;
        const int word = idx & 31;
        const int db   = idx >> 5;
        const int d    = db >> 9;
        const int b    = db & 511;
        const int* src = x + b * T;
        uint32 m = 0;
#pragma unroll 8
        for (int i = 0; i < 32; ++i) {
            const int t = word * 32 + i;
            m |= (src[d ? (T - 1 - t) : t] != 0 ? 1u : 0u) << i;
        }
        mbits[idx] = m;
    } else if (bid < 2048 + 128 + 16) {
        // ---- bfrag: one block per (d, g, ks) ----
        const int bid3 = bid - 2176;      // 0..15
        const int d  = bid3 >> 3;
        const int g  = (bid3 >> 1) & 3;
        const int ks = bid3 & 1;
        const float* U = d ? Ub : Uf;
        const float* W = d ? Wb : Wf;
        const int lane = tid & 63, w = tid >> 6;
        const float scale = (g == 2) ? (2.0f * L2E) : (-L2E);
#pragma unroll
        for (int j = 0; j < 8; ++j) {
            const int col = g * 64 + 16 * w + (lane & 15);
            const int k   = ks * 32 + (lane >> 4) * 8 + j;
            const float uv = U[k * NGATE + col] * scale;
            const u16 uhi = f2bf(uv);
            const u16 ulo = f2bf(uv - bf2f(uhi));
            const u16 whi = f2bf(W[k * NGATE + col] * scale);
            const size_t base = ((((size_t)(d * 4 + w) * 4 + g) * 2 + ks) * 3) * 512;
            bfrag[base + 0 * 512 + lane * 8 + j] = uhi;
            bfrag[base + 1 * 512 + lane * 8 + j] = ulo;
            bfrag[base + 2 * 512 + lane * 8 + j] = whi;
        }
    } else {
        // ---- zero handshake flags (one per (gb16, sub) pair) ----
        if (tid < 128) flags[tid] = 0;
    }
}

// ---------------------------------------------------------------------------
// MFMA LSTM v8 core (verified 286.7 us) + fused MLP tail.
// Loop byte-identical to v8/r10. After hcat store: release fence + atomicAdd
// on the pair flag (d=0/d=1 blocks of the same 4 seqs); the second arrival
// acquires and computes the MLP head for its 4 seqs (64 threads/seq, 2
// k-halves x 32 units, LDS combine + width-32 shuffle reduce — identical
// summation order to the verified standalone mlp v2).
// ---------------------------------------------------------------------------
__global__ __launch_bounds__(256, 1)
void lstm_mfma(const uint32* __restrict__ mbits,
               const u16* __restrict__ xstream,
               const u16* __restrict__ bfragp,
               const float* __restrict__ bf, const float* __restrict__ bb,
               float* __restrict__ hcat, uint32* __restrict__ flags,
               const float* __restrict__ W1, const float* __restrict__ b1,
               const float* __restrict__ W2, const float* __restrict__ b2,
               float* __restrict__ out)
{
    const int tid  = threadIdx.x;
    const int lane = tid & 63;
    const int w    = tid >> 6;          // unit group: units [16w, 16w+16)
    const int col  = lane & 15;
    const int quad = lane >> 4;
    // swizzled decode: sharers of one gb16 are congruent mod 8 -> same XCD
    const int gb16  = blockIdx.x & 31;
    const int inner = blockIdx.x >> 5;  // 0..7
    const int d     = inner >> 2;
    const int sub   = inner & 3;        // seqs 16*gb16 + 4*sub + [0,4)

    const int ucol = 16 * w + col;
    const int KS   = w >> 1;

    // B fragments (per (d,w), shared across sub-blocks): U-hi + W-hi only
    short8 BUh[4][2];   // [g][ks] U-hi
    short8 BW[4][2];    // [g][ks]
    {
        const u16* pb = bfragp + (size_t)(d * 4 + w) * 4 * 2 * 3 * 512;
#pragma unroll
        for (int g = 0; g < 4; ++g)
#pragma unroll
        for (int ks = 0; ks < 2; ++ks) {
            BUh[g][ks] = *(const short8*)&pb[((g * 2 + ks) * 3 + 0) * 512 + lane * 8];
            BW[g][ks]  = *(const short8*)&pb[((g * 2 + ks) * 3 + 2) * 512 + lane * 8];
        }
    }
    float biasv[4];
    {
        const float* bias = d ? bb : bf;
#pragma unroll
        for (int g = 0; g < 4; ++g)
            biasv[g] = bias[g * 64 + ucol] * ((g == 2) ? (2.0f * L2E) : (-L2E));
    }

    __shared__ u16 Ahl[2][2][64][8];     // [buf][ks][kg*16+row][j]; hi rows 4p, lo 4p+1
    {
        u16* f = &Ahl[0][0][0][0];
        for (int i = tid; i < 2 * 2 * 64 * 8; i += 256) f[i] = 0;
    }

    // epilogue identity: this thread owns (seq-local p=quad, unit 16w+col)
    const uint32* mrow = mbits + (size_t)(d * 512 + gb16 * 16 + 4 * sub + quad) * 32;
    uint32 mcur = mrow[0], mnext = mrow[1];
    // h-write target: hi -> A-row 4*quad, lo -> 4*quad+1, k-position from unit
    const int q2u  = (2 * w + (col >> 3)) & 3;
    const int hrow = q2u * 16 + 4 * quad;
    const int hj   = col & 7;

    const u16* sptr = xstream + (size_t)gb16 * 1024 * 1024;

    // xstream lane remap for the 4-step x-batch: A-frag row r = lane&15
    // sources seq 4*sub + (r>>2) at step-chunk base +/- (r&3).
    const int srcoff    = ((lane & 48) | (4 * sub + ((lane & 15) >> 2))) * 8;
    const int lanedelta = srcoff + (d ? -(lane & 3) : (lane & 3)) * 1024;

#define XBATCH(XT, G)                                                          \
    XT[G][0] = biasv[G]; XT[G][1] = biasv[G];                                  \
    XT[G][2] = biasv[G]; XT[G][3] = biasv[G];                                  \
    XT[G] = __builtin_amdgcn_mfma_f32_16x16x32_bf16(axr[0], BW[G][0], XT[G], 0, 0, 0); \
    XT[G] = __builtin_amdgcn_mfma_f32_16x16x32_bf16(axr[1], BW[G][1], XT[G], 0, 0, 0);

    short8 axr[2];
    f32x4  xaccA[4], xaccB[4];
    {   // prologue: load quad-0 chunk, compute xaccA for steps 0..3
        const int c2 = d ? 1023 : 0;
        const u16* cp = sptr + (size_t)c2 * 1024;
        axr[0] = *(const short8*)(cp + lanedelta);
        axr[1] = *(const short8*)(cp + 512 + lanedelta);
        XBATCH(xaccA, 0) XBATCH(xaccA, 1) XBATCH(xaccA, 2) XBATCH(xaccA, 3)
    }
    // persistent C-in registers: xinit[g] lanes [1..3] == 0 forever
    f32x4 xinit[4];
#pragma unroll
    for (int g = 0; g < 4; ++g) { xinit[g][0] = 0.f; xinit[g][1] = 0.f; xinit[g][2] = 0.f; xinit[g][3] = 0.f; }

    __syncthreads();    // once, outside hot loop

    float hv = 0.f, cv = 0.f;

#define STEP(SV, P, XC, XP, QP)                                                \
  {                                                                            \
    if ((QP) == 0) {   /* per-quad axr refill (next quad) + mask window */     \
      const int cs = ((SV) + 4 <= 1020) ? ((SV) + 4) : 1020;                   \
      const int c2 = d ? (1023 - cs) : cs;                                     \
      const u16* cp = sptr + (size_t)c2 * 1024;                                \
      axr[0] = *(const short8*)(cp + lanedelta);                               \
      axr[1] = *(const short8*)(cp + 512 + lanedelta);                         \
      if ((((SV) & 31) == 0) && ((SV) > 0)) {                                  \
        const int wn = ((SV) >> 5) + 1;                                        \
        const int wc = (wn < 32) ? wn : 31;                                    \
        mcur = mnext; mnext = mrow[wc];                                        \
      }                                                                        \
    }                                                                          \
    BARRIER_LDS();                                                             \
    const short8 Ah0 = *(const short8*)&Ahl[1 - (P)][0][lane][0];              \
    const short8 Ah1 = *(const short8*)&Ahl[1 - (P)][1][lane][0];              \
    /* xinit movs + next-quad x-batch fill the ds_read latency */              \
    xinit[0][0] = XC[0][(QP)];                                                 \
    xinit[1][0] = XC[1][(QP)];                                                 \
    xinit[2][0] = XC[2][(QP)];                                                 \
    xinit[3][0] = XC[3][(QP)];                                                 \
    if ((QP) == 2) { XBATCH(XP, 0) XBATCH(XP, 1) }                             \
    if ((QP) == 3) { XBATCH(XP, 2) XBATCH(XP, 3) }                             \
    /* ---- h-part: one 2-deep a-chain per gate (hi+lo rows ride along) ---- */\
    f32x4 a2 = __builtin_amdgcn_mfma_f32_16x16x32_bf16(Ah0, BUh[2][0], xinit[2], 0, 0, 0); \
    a2       = __builtin_amdgcn_mfma_f32_16x16x32_bf16(Ah1, BUh[2][1], a2, 0, 0, 0);       \
    f32x4 a0 = __builtin_amdgcn_mfma_f32_16x16x32_bf16(Ah0, BUh[0][0], xinit[0], 0, 0, 0); \
    a0       = __builtin_amdgcn_mfma_f32_16x16x32_bf16(Ah1, BUh[0][1], a0, 0, 0, 0);       \
    f32x4 a1 = __builtin_amdgcn_mfma_f32_16x16x32_bf16(Ah0, BUh[1][0], xinit[1], 0, 0, 0); \
    a1       = __builtin_amdgcn_mfma_f32_16x16x32_bf16(Ah1, BUh[1][1], a1, 0, 0, 0);       \
    f32x4 a3 = __builtin_amdgcn_mfma_f32_16x16x32_bf16(Ah0, BUh[3][0], xinit[3], 0, 0, 0); \
    a3       = __builtin_amdgcn_mfma_f32_16x16x32_bf16(Ah1, BUh[3][1], a3, 0, 0, 0);       \
    /* ---- epilogue, dependency-ordered: cn chain starts earliest ---- */     \
    {                                                                          \
      const float gg = a2[0] + a2[1];                                          \
      const float gv = tanh_pre(gg);                                           \
      const float gi = a0[0] + a0[1];                                          \
      const float iv = sigm_pre(gi);                                           \
      const float gf = a1[0] + a1[1];                                          \
      const float fv = sigm_pre(gf);                                           \
      const float ig = iv * gv;                                                \
      const float cn = fmaf(fv, cv, ig);                                       \
      const float go = a3[0] + a3[1];                                          \
      const float ov = sigm_pre(go);                                           \
      const float th = tanh_c(cn);                                             \
      const float hn = ov * th;                                                \
      if ((mcur >> ((SV) & 31)) & 1) { cv = cn; hv = hn; }                     \
      const uint32 uh = __float_as_uint(hv);                                   \
      const u16 hhi = (u16)(uh >> 16);                                         \
      const u16 hlo = (u16)(__float_as_uint(hv - bf2f(hhi)) >> 16);            \
      Ahl[(P)][KS][hrow][hj]     = hhi;                                        \
      Ahl[(P)][KS][hrow + 1][hj] = hlo;                                        \
    }                                                                          \
  }

    for (int s = 0; s < T; s += 8) {
        STEP(s,     0, xaccA, xaccB, 0)
        STEP(s + 1, 1, xaccA, xaccB, 1)
        STEP(s + 2, 0, xaccA, xaccB, 2)
        STEP(s + 3, 1, xaccA, xaccB, 3)
        STEP(s + 4, 0, xaccB, xaccA, 0)
        STEP(s + 5, 1, xaccB, xaccA, 1)
        STEP(s + 6, 0, xaccB, xaccA, 2)
        STEP(s + 7, 1, xaccB, xaccA, 3)
    }
#undef STEP
#undef XBATCH

    hcat[(size_t)(gb16 * 16 + 4 * sub + quad) * (2 * HID) + d * HID + ucol] = hv;

    // ---- fused MLP head: pair handshake (d=0 / d=1 blocks of same seqs) ----
    __threadfence();                          // release: hcat visible
    __shared__ uint32 winls;
    if (tid == 0) winls = atomicAdd(&flags[gb16 * 4 + sub], 1u);
    __syncthreads();
    if (winls == 1) {                         // second arrival runs the MLP
        __threadfence();                      // acquire: partner's hcat visible
        float* part = (float*)&Ahl[0][0][0][0];   // reuse LDS: [p][kh][m]
        const int p  = tid >> 6;              // seq-local 0..3 (one wave each)
        const int m  = tid & 31;
        const int kh = (tid >> 5) & 1;        // k-half
        const int seq = gb16 * 16 + 4 * sub + p;
        const float* h = hcat + (size_t)seq * (2 * HID);
        float acc = (kh == 0) ? b1[m] : 0.0f;
#pragma unroll
        for (int k = 0; k < 64; ++k)
            acc += h[kh * 64 + k] * W1[(kh * 64 + k) * 32 + m];
        part[(p * 2 + kh) * 32 + m] = acc;
        __syncthreads();
        if ((tid & 63) < 32) {
            const float h1 = fmaxf(part[(p * 2) * 32 + m] + part[(p * 2 + 1) * 32 + m], 0.0f);
            float v = h1 * W2[m];
#pragma unroll
            for (int o = 16; o > 0; o >>= 1) v += __shfl_down(v, o, 32);
            if (m == 0) out[seq] = v + b2[0];
        }
    }
}

extern "C" void kernel_launch(void* const* d_in, const int* in_sizes, int n_in,
                              void* d_out, int out_size, void* d_ws, size_t ws_size,
                              hipStream_t stream)
{
    const int*   x   = (const int*)d_in[0];
    const float* emb = (const float*)d_in[1];
    const float* Wf  = (const float*)d_in[2];
    const float* Uf  = (const float*)d_in[3];
    const float* bf  = (const float*)d_in[4];
    const float* Wb  = (const float*)d_in[5];
    const float* Ub  = (const float*)d_in[6];
    const float* bb  = (const float*)d_in[7];
    const float* W1  = (const float*)d_in[8];
    const float* b1  = (const float*)d_in[9];
    const float* W2  = (const float*)d_in[10];
    const float* b2  = (const float*)d_in[11];
    float* out = (float*)d_out;

    // workspace: [xstream 64MB | mbits | bfrag | hcat | flags]
    u16*    xstream = (u16*)d_ws;                           // 32*1024*128*8 u16
    uint32* mbits   = (uint32*)(xstream + (size_t)32 * 1024 * 1024);  // 2*512*32 u32
    u16*    bfragp  = (u16*)(mbits + 2 * 512 * 32);         // 98304 u16
    float*  hcat    = (float*)(bfragp + 98304);             // 512*128 f32
    uint32* flags   = (uint32*)(hcat + 512 * 128);          // 128 u32

    prep_kernel<<<dim3(2048 + 128 + 16 + 1), dim3(256), 0, stream>>>(
        x, emb, Uf, Ub, Wf, Wb, xstream, mbits, bfragp, flags);
    lstm_mfma<<<dim3(256), dim3(256), 0, stream>>>(
        mbits, xstream, bfragp, bf, bb, hcat, flags, W1, b1, W2, b2, out);
}

// Round 12
// 378.713 us; speedup vs baseline: 1.0524x; 1.0524x over previous
//
#include <hip/hip_runtime.h>

#define T 1024
#define BATCH 512
#define EMB 64
#define HID 64
#define NGATE 256
#define VOCABP1 50001

typedef unsigned int uint32;
typedef unsigned short u16;
typedef __attribute__((ext_vector_type(8))) short short8;   // 8 bf16 = 4 VGPRs
typedef __attribute__((ext_vector_type(4))) float f32x4;    // MFMA C/D
typedef __attribute__((ext_vector_type(4))) float float4v;
typedef __attribute__((ext_vector_type(4))) int int4v;

#define L2E 1.44269504088896340736f

__device__ __forceinline__ float rcpf(float x) { return __builtin_amdgcn_rcpf(x); }
__device__ __forceinline__ float exp2as(float x) {   // raw v_exp_f32 (= 2^x)
    float r;
    asm("v_exp_f32 %0, %1" : "=v"(r) : "v"(x));
    return r;
}
// gate activations on PRE-SCALED z (weights folded with -log2e / 2log2e):
__device__ __forceinline__ float sigm_pre(float z)  { return rcpf(1.0f + exp2as(z)); }
__device__ __forceinline__ float tanh_pre(float z)  { return fmaf(-2.0f, rcpf(exp2as(z) + 1.0f), 1.0f); }
__device__ __forceinline__ float tanh_c(float c)    { return tanh_pre(c * (2.0f * L2E)); }

__device__ __forceinline__ u16 f2bf(float x) {        // RNE f32->bf16
    uint32 u = __float_as_uint(x);
    u += 0x7fffu + ((u >> 16) & 1u);
    return (u16)(u >> 16);
}
__device__ __forceinline__ float bf2f(u16 h) { return __uint_as_float(((uint32)h) << 16); }

// LDS-only barrier: drains lgkmcnt but leaves global loads in flight.
#define BARRIER_LDS() asm volatile("s_waitcnt lgkmcnt(0)\n\ts_barrier" ::: "memory")

// ---------------------------------------------------------------------------
// Fused prep: ONE dispatch covering
//   blocks [0,2048):    xstream  — A-fragment emb stream, f32->bf16
//   blocks [2048,2176): maskprep — mask bit-words
//   blocks [2176,2192): bfrag    — B fragments, 16-way parallel
// NOTE (r9 lesson): the xstream precompute is load-bearing — its 2048-block
// dispatch has the TLP to absorb the random emb gather; inlining the gather
// into the 1-wave/SIMD lstm loop regressed 290->427 us (FETCH 50->82 MB).
// NOTE (r11 lesson): do NOT fuse the MLP into lstm_mfma — the extra args/
// tail perturb the latency-tuned loop's codegen (287->312 us, VGPR 76->96).
// ---------------------------------------------------------------------------
__global__ void prep_kernel(const int* __restrict__ x, const float* __restrict__ emb,
                            const float* __restrict__ Uf, const float* __restrict__ Ub,
                            const float* __restrict__ Wf, const float* __restrict__ Wb,
                            u16* __restrict__ xstream, uint32* __restrict__ mbits,
                            u16* __restrict__ bfrag)
{
    const int bid = blockIdx.x;
    const int tid = threadIdx.x;

    if (bid < 2048) {
        // ---- xstream ----
        const int gb    = bid >> 6;
        const int stile = bid & 63;
        const int lane  = tid & 63;
        const int half  = tid >> 6;
        const int ks    = half & 1;
        const int sp    = half >> 1;
        const int m     = lane & 15;
        const int qj    = (lane >> 4) * 8;
        // 8 consecutive tokens as 2 x int4 (base 32B-aligned)
        const int4v* xp = (const int4v*)(x + (gb * 16 + m) * T + stile * 16 + sp * 8);
        const int4v t0 = xp[0];
        const int4v t1 = xp[1];
#pragma unroll
        for (int i = 0; i < 8; ++i) {
            const int s   = stile * 16 + sp * 8 + i;
            const int tok = (i < 4) ? t0[i & 3] : t1[i & 3];
            const float* er = emb + (size_t)tok * EMB + ks * 32 + qj;
            const float4v a = *(const float4v*)er;
            const float4v b = *(const float4v*)(er + 4);
            short8 v;
            v[0] = (short)f2bf(a[0]); v[1] = (short)f2bf(a[1]);
            v[2] = (short)f2bf(a[2]); v[3] = (short)f2bf(a[3]);
            v[4] = (short)f2bf(b[0]); v[5] = (short)f2bf(b[1]);
            v[6] = (short)f2bf(b[2]); v[7] = (short)f2bf(b[3]);
            *(short8*)(xstream + ((size_t)(gb * 1024 + s) * 128 + ks * 64 + lane) * 8) = v;
        }
    } else if (bid < 2048 + 128) {
        // ---- maskprep ----
        const int idx  = (bid - 2048) * 256 + tid;
        const int word = idx & 31;
        const int db   = idx >> 5;
        const int d    = db >> 9;
        const int b    = db & 511;
        const int* src = x + b * T;
        uint32 m = 0;
#pragma unroll 8
        for (int i = 0; i < 32; ++i) {
            const int t = word * 32 + i;
            m |= (src[d ? (T - 1 - t) : t] != 0 ? 1u : 0u) << i;
        }
        mbits[idx] = m;
    } else {
        // ---- bfrag: one block per (d, g, ks) ----
        const int bid3 = bid - 2176;      // 0..15
        const int d  = bid3 >> 3;
        const int g  = (bid3 >> 1) & 3;
        const int ks = bid3 & 1;
        const float* U = d ? Ub : Uf;
        const float* W = d ? Wb : Wf;
        const int lane = tid & 63, w = tid >> 6;
        const float scale = (g == 2) ? (2.0f * L2E) : (-L2E);
#pragma unroll
        for (int j = 0; j < 8; ++j) {
            const int col = g * 64 + 16 * w + (lane & 15);
            const int k   = ks * 32 + (lane >> 4) * 8 + j;
            const float uv = U[k * NGATE + col] * scale;
            const u16 uhi = f2bf(uv);
            const u16 ulo = f2bf(uv - bf2f(uhi));
            const u16 whi = f2bf(W[k * NGATE + col] * scale);
            const size_t base = ((((size_t)(d * 4 + w) * 4 + g) * 2 + ks) * 3) * 512;
            bfrag[base + 0 * 512 + lane * 8 + j] = uhi;
            bfrag[base + 1 * 512 + lane * 8 + j] = ulo;
            bfrag[base + 2 * 512 + lane * 8 + j] = whi;
        }
    }
}

// ---------------------------------------------------------------------------
// MFMA LSTM v8 (verified 286.7 us): 10 MFMAs/step/wave. a-chains (A x U-hi)
// deliver h_hi*Uhi (reg0) and h_lo*Uhi (reg1) in the same MFMAs; recurrent
// state precision preserved (h hi/lo rows 4p/4p+1, c in f32). U-lo chains
// dropped (measured bit-identical absmax). Direct-gather variant REGRESSED
// (r9); MLP-fusion variant REGRESSED (r11) — keep this kernel minimal.
// ---------------------------------------------------------------------------
__global__ __launch_bounds__(256, 1)
void lstm_mfma(const uint32* __restrict__ mbits,
               const u16* __restrict__ xstream,
               const u16* __restrict__ bfragp,
               const float* __restrict__ bf, const float* __restrict__ bb,
               float* __restrict__ hcat)
{
    const int tid  = threadIdx.x;
    const int lane = tid & 63;
    const int w    = tid >> 6;          // unit group: units [16w, 16w+16)
    const int col  = lane & 15;
    const int quad = lane >> 4;
    // swizzled decode: sharers of one gb16 are congruent mod 8 -> same XCD
    const int gb16  = blockIdx.x & 31;
    const int inner = blockIdx.x >> 5;  // 0..7
    const int d     = inner >> 2;
    const int sub   = inner & 3;        // seqs 16*gb16 + 4*sub + [0,4)

    const int ucol = 16 * w + col;
    const int KS   = w >> 1;

    // B fragments (per (d,w), shared across sub-blocks): U-hi + W-hi only
    short8 BUh[4][2];   // [g][ks] U-hi
    short8 BW[4][2];    // [g][ks]
    {
        const u16* pb = bfragp + (size_t)(d * 4 + w) * 4 * 2 * 3 * 512;
#pragma unroll
        for (int g = 0; g < 4; ++g)
#pragma unroll
        for (int ks = 0; ks < 2; ++ks) {
            BUh[g][ks] = *(const short8*)&pb[((g * 2 + ks) * 3 + 0) * 512 + lane * 8];
            BW[g][ks]  = *(const short8*)&pb[((g * 2 + ks) * 3 + 2) * 512 + lane * 8];
        }
    }
    float biasv[4];
    {
        const float* bias = d ? bb : bf;
#pragma unroll
        for (int g = 0; g < 4; ++g)
            biasv[g] = bias[g * 64 + ucol] * ((g == 2) ? (2.0f * L2E) : (-L2E));
    }

    __shared__ u16 Ahl[2][2][64][8];     // [buf][ks][kg*16+row][j]; hi rows 4p, lo 4p+1
    {
        u16* f = &Ahl[0][0][0][0];
        for (int i = tid; i < 2 * 2 * 64 * 8; i += 256) f[i] = 0;
    }

    // epilogue identity: this thread owns (seq-local p=quad, unit 16w+col)
    const uint32* mrow = mbits + (size_t)(d * 512 + gb16 * 16 + 4 * sub + quad) * 32;
    uint32 mcur = mrow[0], mnext = mrow[1];
    // h-write target: hi -> A-row 4*quad, lo -> 4*quad+1, k-position from unit
    const int q2u  = (2 * w + (col >> 3)) & 3;
    const int hrow = q2u * 16 + 4 * quad;
    const int hj   = col & 7;

    const u16* sptr = xstream + (size_t)gb16 * 1024 * 1024;

    // xstream lane remap for the 4-step x-batch: A-frag row r = lane&15
    // sources seq 4*sub + (r>>2) at step-chunk base +/- (r&3).
    const int srcoff    = ((lane & 48) | (4 * sub + ((lane & 15) >> 2))) * 8;
    const int lanedelta = srcoff + (d ? -(lane & 3) : (lane & 3)) * 1024;

#define XBATCH(XT, G)                                                          \
    XT[G][0] = biasv[G]; XT[G][1] = biasv[G];                                  \
    XT[G][2] = biasv[G]; XT[G][3] = biasv[G];                                  \
    XT[G] = __builtin_amdgcn_mfma_f32_16x16x32_bf16(axr[0], BW[G][0], XT[G], 0, 0, 0); \
    XT[G] = __builtin_amdgcn_mfma_f32_16x16x32_bf16(axr[1], BW[G][1], XT[G], 0, 0, 0);

    short8 axr[2];
    f32x4  xaccA[4], xaccB[4];
    {   // prologue: load quad-0 chunk, compute xaccA for steps 0..3
        const int c2 = d ? 1023 : 0;
        const u16* cp = sptr + (size_t)c2 * 1024;
        axr[0] = *(const short8*)(cp + lanedelta);
        axr[1] = *(const short8*)(cp + 512 + lanedelta);
        XBATCH(xaccA, 0) XBATCH(xaccA, 1) XBATCH(xaccA, 2) XBATCH(xaccA, 3)
    }
    // persistent C-in registers: xinit[g] lanes [1..3] == 0 forever
    f32x4 xinit[4];
#pragma unroll
    for (int g = 0; g < 4; ++g) { xinit[g][0] = 0.f; xinit[g][1] = 0.f; xinit[g][2] = 0.f; xinit[g][3] = 0.f; }

    __syncthreads();    // once, outside hot loop

    float hv = 0.f, cv = 0.f;

#define STEP(SV, P, XC, XP, QP)                                                \
  {                                                                            \
    if ((QP) == 0) {   /* per-quad axr refill (next quad) + mask window */     \
      const int cs = ((SV) + 4 <= 1020) ? ((SV) + 4) : 1020;                   \
      const int c2 = d ? (1023 - cs) : cs;                                     \
      const u16* cp = sptr + (size_t)c2 * 1024;                                \
      axr[0] = *(const short8*)(cp + lanedelta);                               \
      axr[1] = *(const short8*)(cp + 512 + lanedelta);                         \
      if ((((SV) & 31) == 0) && ((SV) > 0)) {                                  \
        const int wn = ((SV) >> 5) + 1;                                        \
        const int wc = (wn < 32) ? wn : 31;                                    \
        mcur = mnext; mnext = mrow[wc];                                       \
      }                                                                        \
    }                                                                          \
    BARRIER_LDS();                                                             \
    const short8 Ah0 = *(const short8*)&Ahl[1 - (P)][0][lane][0];              \
    const short8 Ah1 = *(const short8*)&Ahl[1 - (P)][1][lane][0];              \
    /* xinit movs + next-quad x-batch fill the ds_read latency */              \
    xinit[0][0] = XC[0][(QP)];                                                 \
    xinit[1][0] = XC[1][(QP)];                                                 \
    xinit[2][0] = XC[2][(QP)];                                                 \
    xinit[3][0] = XC[3][(QP)];                                                 \
    if ((QP) == 2) { XBATCH(XP, 0) XBATCH(XP, 1) }                             \
    if ((QP) == 3) { XBATCH(XP, 2) XBATCH(XP, 3) }                             \
    /* ---- h-part: one 2-deep a-chain per gate (hi+lo rows ride along) ---- */\
    f32x4 a2 = __builtin_amdgcn_mfma_f32_16x16x32_bf16(Ah0, BUh[2][0], xinit[2], 0, 0, 0); \
    a2       = __builtin_amdgcn_mfma_f32_16x16x32_bf16(Ah1, BUh[2][1], a2, 0, 0, 0);       \
    f32x4 a0 = __builtin_amdgcn_mfma_f32_16x16x32_bf16(Ah0, BUh[0][0], xinit[0], 0, 0, 0); \
    a0       = __builtin_amdgcn_mfma_f32_16x16x32_bf16(Ah1, BUh[0][1], a0, 0, 0, 0);       \
    f32x4 a1 = __builtin_amdgcn_mfma_f32_16x16x32_bf16(Ah0, BUh[1][0], xinit[1], 0, 0, 0); \
    a1       = __builtin_amdgcn_mfma_f32_16x16x32_bf16(Ah1, BUh[1][1], a1, 0, 0, 0);       \
    f32x4 a3 = __builtin_amdgcn_mfma_f32_16x16x32_bf16(Ah0, BUh[3][0], xinit[3], 0, 0, 0); \
    a3       = __builtin_amdgcn_mfma_f32_16x16x32_bf16(Ah1, BUh[3][1], a3, 0, 0, 0);       \
    /* ---- epilogue, dependency-ordered: cn chain starts earliest ---- */     \
    {                                                                          \
      const float gg = a2[0] + a2[1];                                          \
      const float gv = tanh_pre(gg);                                           \
      const float gi = a0[0] + a0[1];                                          \
      const float iv = sigm_pre(gi);                                           \
      const float gf = a1[0] + a1[1];                                          \
      const float fv = sigm_pre(gf);                                           \
      const float ig = iv * gv;                                                \
      const float cn = fmaf(fv, cv, ig);                                       \
      const float go = a3[0] + a3[1];                                          \
      const float ov = sigm_pre(go);                                           \
      const float th = tanh_c(cn);                                             \
      const float hn = ov * th;                                                \
      if ((mcur >> ((SV) & 31)) & 1) { cv = cn; hv = hn; }                     \
      const uint32 uh = __float_as_uint(hv);                                   \
      const u16 hhi = (u16)(uh >> 16);                                         \
      const u16 hlo = (u16)(__float_as_uint(hv - bf2f(hhi)) >> 16);            \
      Ahl[(P)][KS][hrow][hj]     = hhi;                                        \
      Ahl[(P)][KS][hrow + 1][hj] = hlo;                                        \
    }                                                                          \
  }

    for (int s = 0; s < T; s += 8) {
        STEP(s,     0, xaccA, xaccB, 0)
        STEP(s + 1, 1, xaccA, xaccB, 1)
        STEP(s + 2, 0, xaccA, xaccB, 2)
        STEP(s + 3, 1, xaccA, xaccB, 3)
        STEP(s + 4, 0, xaccB, xaccA, 0)
        STEP(s + 5, 1, xaccB, xaccA, 1)
        STEP(s + 6, 0, xaccB, xaccA, 2)
        STEP(s + 7, 1, xaccB, xaccA, 3)
    }
#undef STEP
#undef XBATCH

    hcat[(size_t)(gb16 * 16 + 4 * sub + quad) * (2 * HID) + d * HID + ucol] = hv;
}

// ---------------------------------------------------------------------------
// MLP head v2: out[b] = relu(hcat[b] @ W1 + b1) @ W2 + b2
// 64 threads: unit m = tid&31 split over 2 k-halves (tid>>5), LDS combine,
// then 32-lane shuffle-reduce for the final dot.
// ---------------------------------------------------------------------------
__global__ void mlp_kernel(const float* __restrict__ hcat,
                           const float* __restrict__ W1, const float* __restrict__ b1,
                           const float* __restrict__ W2, const float* __restrict__ b2,
                           float* __restrict__ out)
{
    const int b   = blockIdx.x;
    const int tid = threadIdx.x;
    const int m   = tid & 31;
    const int kh  = tid >> 5;          // 0,1: k in [64*kh, 64*kh+64)
    __shared__ float part[2][32];
    const float* h = hcat + b * (2 * HID);

    float acc = (kh == 0) ? b1[m] : 0.0f;
#pragma unroll
    for (int k = 0; k < 64; ++k) acc += h[kh * 64 + k] * W1[(kh * 64 + k) * 32 + m];
    part[kh][m] = acc;
    __syncthreads();
    if (tid < 32) {
        const float h1 = fmaxf(part[0][tid] + part[1][tid], 0.0f);
        float v = h1 * W2[tid];
#pragma unroll
        for (int o = 16; o > 0; o >>= 1) v += __shfl_down(v, o);
        if (tid == 0) out[b] = v + b2[0];
    }
}

extern "C" void kernel_launch(void* const* d_in, const int* in_sizes, int n_in,
                              void* d_out, int out_size, void* d_ws, size_t ws_size,
                              hipStream_t stream)
{
    const int*   x   = (const int*)d_in[0];
    const float* emb = (const float*)d_in[1];
    const float* Wf  = (const float*)d_in[2];
    const float* Uf  = (const float*)d_in[3];
    const float* bf  = (const float*)d_in[4];
    const float* Wb  = (const float*)d_in[5];
    const float* Ub  = (const float*)d_in[6];
    const float* bb  = (const float*)d_in[7];
    const float* W1  = (const float*)d_in[8];
    const float* b1  = (const float*)d_in[9];
    const float* W2  = (const float*)d_in[10];
    const float* b2  = (const float*)d_in[11];
    float* out = (float*)d_out;

    // workspace: [xstream 64MB | mbits | bfrag | hcat]
    u16*    xstream = (u16*)d_ws;                           // 32*1024*128*8 u16
    uint32* mbits   = (uint32*)(xstream + (size_t)32 * 1024 * 1024);  // 2*512*32 u32
    u16*    bfragp  = (u16*)(mbits + 2 * 512 * 32);         // 98304 u16
    float*  hcat    = (float*)(bfragp + 98304);             // 512*128 f32

    prep_kernel<<<dim3(2048 + 128 + 16), dim3(256), 0, stream>>>(
        x, emb, Uf, Ub, Wf, Wb, xstream, mbits, bfragp);
    lstm_mfma<<<dim3(256), dim3(256), 0, stream>>>(mbits, xstream, bfragp, bf, bb, hcat);
    mlp_kernel<<<dim3(BATCH), dim3(64), 0, stream>>>(hcat, W1, b1, W2, b2, out);
}